// Round 7
// baseline (158.400 us; speedup 1.0000x reference)
//
#include <hip/hip_runtime.h>

// SecurePooling: x (32,1000,14,14) f32 -> pred (32,) int32
// Even-coordinate SAT S[r][c] = sum(x[0:2r,0:2c]), r,c in 0..7 is a complete
// sufficient statistic. 351 streams per b: 325 unordered pairs (two[p][q]),
// 25 one-mask, 1 total.  Argmax over c per stream, first-index tie-break.
// kernB: lane=c, wave=64-class chunk; streams split into 8 groups of 44
// (template<G>, compile-time SID range) so the per-wave live set fits in
// registers (R6 spilled at 96 VGPRs with all 351 streams per wave), and the
// grid is 8x larger (4096 waves = 4/SIMD) to hide VALU/DPP latency.

#define NC 1000
#define NBC 32000   // 32*1000
#define NCH 16      // c-chunks of 64 (chunk 15 overlaps: c0=936)
#define PSTRIDE 384
#define GSZ 44      // streams per group; 8 groups cover 352 >= 351

__host__ __device__ constexpr int tri_off(int p) { return p * 25 - p * (p - 1) / 2; }

// ---------------- Kernel A: per-(b,c) even SAT, LDS-staged coalesced ----------------
__global__ __launch_bounds__(256) void satA(const float* __restrict__ x,
                                            float* __restrict__ Sws) {
    __shared__ float lx[64 * 197];                       // odd stride: conflict-free
    const int tid = threadIdx.x;
    const int blk = blockIdx.x;                          // 500 blocks x 64 images
    const float4* x4 = reinterpret_cast<const float4*>(x) + (size_t)blk * 3136;
#pragma unroll
    for (int it = 0; it < 13; ++it) {
        int f = it * 256 + tid;                          // 3136 float4 per block
        if (f < 3136) {
            float4 v = x4[f];
            int img = f / 49;
            int off = f - img * 49;
            float* d = &lx[img * 197 + off * 4];
            d[0] = v.x; d[1] = v.y; d[2] = v.z; d[3] = v.w;
        }
    }
    __syncthreads();
    if (tid < 64) {
        const float* im = &lx[tid * 197];
        float S[8][8];
#pragma unroll
        for (int c = 0; c < 8; ++c) S[0][c] = 0.f;
        float colacc[7];
#pragma unroll
        for (int c = 0; c < 7; ++c) colacc[c] = 0.f;
#pragma unroll
        for (int r = 0; r < 7; ++r) {
            float rowf[28];
#pragma unroll
            for (int j = 0; j < 28; ++j) rowf[j] = im[r * 28 + j];
            S[r + 1][0] = 0.f;
            float run = 0.f;
#pragma unroll
            for (int c = 0; c < 7; ++c) {
                float blk2 = rowf[2 * c] + rowf[2 * c + 1] + rowf[14 + 2 * c] + rowf[14 + 2 * c + 1];
                colacc[c] += blk2;
                run += colacc[c];
                S[r + 1][c + 1] = run;
            }
        }
        const int bc = blk * 64 + tid;
#pragma unroll
        for (int k = 0; k < 64; ++k)
            Sws[(size_t)k * NBC + bc] = S[k >> 3][k & 7];
    }
}

// ---------------- Kernel B: grouped streams, DPP wave argmax ----------------
template <int CTRL>
__device__ __forceinline__ float dppmax(float v) {
    int o = __builtin_amdgcn_update_dpp(__float_as_int(v), __float_as_int(v),
                                        CTRL, 0xF, 0xF, false);
    return fmaxf(v, __int_as_float(o));
}

template <int G>
__device__ __forceinline__ void procB(const float* __restrict__ Sws,
                                      unsigned long long* __restrict__ part,
                                      int b, int wc, int c0, int lane) {
    constexpr int SBASE = G * GSZ;
    constexpr int SEND = (SBASE + GSZ < 351) ? SBASE + GSZ : 351;
    const int c = c0 + lane;

    float S[64];
#pragma unroll
    for (int k = 0; k < 64; ++k)
        S[k] = Sws[(size_t)k * NBC + b * NC + c];        // unused k's DCE away
    const float total = S[63];

    // window sums (same FP order as verified R2/R6 kernels); unused DCE away
    float w_[25];
#pragma unroll
    for (int p1 = 0; p1 < 5; ++p1)
#pragma unroll
        for (int p2 = 0; p2 < 5; ++p2)
            w_[p1 * 5 + p2] = ((S[(p1 + 3) * 8 + (p2 + 3)] - S[p1 * 8 + (p2 + 3)])
                               - S[(p1 + 3) * 8 + p2]) + S[p1 * 8 + p2];

    int rs_lo = 0, rs_hi = 0;                            // this group's <=44 slots

    // DPP chain: row_shr 1,2,4,8 then row_bcast15, row_bcast31 -> lane63 has max.
#define EMIT(VAL, SID)                                                          \
    if ((SID) >= SBASE && (SID) < SEND) {                                       \
        float _v = (VAL);                                                       \
        float _m = _v;                                                          \
        _m = dppmax<0x111>(_m); _m = dppmax<0x112>(_m);                         \
        _m = dppmax<0x114>(_m); _m = dppmax<0x118>(_m);                         \
        _m = dppmax<0x142>(_m); _m = dppmax<0x143>(_m);                         \
        int _mb = __builtin_amdgcn_readlane(__float_as_int(_m), 63);            \
        unsigned long long _eq = __ballot(__float_as_int(_v) == _mb);           \
        int _off = __ffsll(_eq) - 1;                                            \
        unsigned _cw = (unsigned)(c0 + _off);                                   \
        unsigned _u = (unsigned)_mb;                                            \
        unsigned _fk = _u ^ (unsigned)(((int)_u >> 31) | 0x80000000);           \
        if (lane == ((SID) - SBASE)) { rs_lo = (int)~_cw; rs_hi = (int)_fk; }   \
    }

    // 325 unordered pairs: v = ((total - w[p]) - w[q]) + rect   (R2 FP order)
#pragma unroll
    for (int p = 0; p < 25; ++p) {
        const float ltp = total - w_[p];
#pragma unroll
        for (int q = 0; q < 25; ++q) {
            if (q < p) continue;
            const int sid = tri_off(p) + (q - p);
            if (sid < SBASE || sid >= SEND) continue;
            const int p1 = p / 5, p2 = p % 5, q1 = q / 5, q2 = q % 5;
            const int rlo = (p1 > q1 ? p1 : q1);
            const int rmn = (p1 < q1 ? p1 : q1);
            const int rhi = (rmn + 3 > rlo ? rmn + 3 : rlo);
            const int clo = (p2 > q2 ? p2 : q2);
            const int cmn = (p2 < q2 ? p2 : q2);
            const int chi = (cmn + 3 > clo ? cmn + 3 : clo);
            const float rect = ((S[rhi * 8 + chi] - S[rlo * 8 + chi])
                                - S[rhi * 8 + clo]) + S[rlo * 8 + clo];
            const float v = (ltp - w_[q]) + rect;
            EMIT(v, sid);
        }
    }
    // 25 one-mask streams + total stream
#pragma unroll
    for (int i = 0; i < 25; ++i) EMIT(total - w_[i], 325 + i);
    EMIT(total, 350);
#undef EMIT

    if (lane < SEND - SBASE)
        part[(size_t)(b * NCH + wc) * PSTRIDE + SBASE + lane] =
            ((unsigned long long)(unsigned)rs_hi << 32) | (unsigned)rs_lo;
}

__global__ __launch_bounds__(128, 1) void kernB(const float* __restrict__ Sws,
                                                unsigned long long* __restrict__ part) {
    const int tid = threadIdx.x;
    const int lane = tid & 63;
    const int bid = blockIdx.x;                          // b*64 + wc*4 + gpair
    const int b = bid >> 6;
    const int wc = (bid >> 2) & 15;
    const int g = ((bid & 3) << 1) + (tid >> 6);         // 0..7, wave-uniform
    const int c0 = (wc == 15) ? 936 : wc * 64;           // chunk 15 overlaps 14
    switch (g) {
        case 0: procB<0>(Sws, part, b, wc, c0, lane); break;
        case 1: procB<1>(Sws, part, b, wc, c0, lane); break;
        case 2: procB<2>(Sws, part, b, wc, c0, lane); break;
        case 3: procB<3>(Sws, part, b, wc, c0, lane); break;
        case 4: procB<4>(Sws, part, b, wc, c0, lane); break;
        case 5: procB<5>(Sws, part, b, wc, c0, lane); break;
        case 6: procB<6>(Sws, part, b, wc, c0, lane); break;
        case 7: procB<7>(Sws, part, b, wc, c0, lane); break;
    }
}

// ---------------- Kernel C: merge chunks + final decision ----------------
__global__ __launch_bounds__(128) void kernC(const unsigned long long* __restrict__ part,
                                             int* __restrict__ out) {
    __shared__ unsigned long long mg[352];
    const int b = blockIdx.x;
    const int t = threadIdx.x;
    for (int s = t; s < 352; s += 128) {
        unsigned long long m = 0ull;
#pragma unroll
        for (int wc = 0; wc < NCH; ++wc) {
            unsigned long long v = part[(size_t)(b * NCH + wc) * PSTRIDE + s];
            if (v > m) m = v;
        }
        mg[s] = m;
    }
    __syncthreads();
    if (t < 64) {
        const unsigned predidx = (unsigned)mg[350];
        const int pred = (int)~predidx;
        bool cand = false;
        int p1 = 0;
        if (t < 25) {
            const unsigned p1i = (unsigned)mg[325 + t];
            p1 = (int)~p1i;
            bool ag = true;
            for (int j = 0; j < 25; ++j) {
                const int a = t < j ? t : j;
                const int q = t < j ? j : t;
                ag = ag && ((unsigned)mg[tri_off(a) + (q - a)] == p1i);
            }
            cand = ag && (p1 != pred);
        }
        const unsigned long long mask = __ballot(cand);
        int ans = pred;
        if (mask) ans = __shfl(p1, __ffsll(mask) - 1, 64);
        if (t == 0) out[b] = ans;
    }
}

extern "C" void kernel_launch(void* const* d_in, const int* in_sizes, int n_in,
                              void* d_out, int out_size, void* d_ws, size_t ws_size,
                              hipStream_t stream) {
    const float* x = (const float*)d_in[0];
    int* out = (int*)d_out;

    float* Sws = (float*)d_ws;                                    // 8.192 MB
    unsigned long long* part =
        (unsigned long long*)((char*)d_ws + (size_t)64 * NBC * 4); // 32*16*384*8 = 1.57 MB

    satA<<<NBC / 64, 256, 0, stream>>>(x, Sws);
    kernB<<<32 * NCH * 4, 128, 0, stream>>>(Sws, part);
    kernC<<<32, 128, 0, stream>>>(part, out);
}

// Round 8
// 84.225 us; speedup vs baseline: 1.8807x; 1.8807x over previous
//
#include <hip/hip_runtime.h>

// SecurePooling: x (32,1000,14,14) f32 -> pred (32,) int32
// Even-coordinate SAT S[r][c] = sum(x[0:2r,0:2c]), r,c in 0..7 is a complete
// sufficient statistic. 351 streams per b: 325 unordered pairs (two[p][q]),
// 25 one-mask, 1 total.  Argmax over c per stream, first-index tie-break.
//
// kernB (R8 rewrite): S lives in LDS per block (register spills killed R6/R7).
// Block = (b, 64-class chunk), 512 threads. Phase 1: stage S[64] x 64 c's into
// LDS. Phase 2: W[c][27] = {25 window sums, total, 0}. Phase 3: lane = stream,
// serial argmax over the 64 c's, ~8 conflict-free LDS reads/iter, no
// cross-lane ops, ~15 live registers -> no spills by construction.

#define NC 1000
#define NBC 32000   // 32*1000
#define NCH 16      // c-chunks of 64 (chunk 15 overlaps: c0=936)
#define PSTRIDE 384

__host__ __device__ constexpr int tri_off(int p) { return p * 25 - p * (p - 1) / 2; }

// ---------------- Kernel A: per-(b,c) even SAT, LDS-staged coalesced ----------------
__global__ __launch_bounds__(256) void satA(const float* __restrict__ x,
                                            float* __restrict__ Sws) {
    __shared__ float lx[64 * 197];                       // odd stride: conflict-free
    const int tid = threadIdx.x;
    const int blk = blockIdx.x;                          // 500 blocks x 64 images
    const float4* x4 = reinterpret_cast<const float4*>(x) + (size_t)blk * 3136;
#pragma unroll
    for (int it = 0; it < 13; ++it) {
        int f = it * 256 + tid;                          // 3136 float4 per block
        if (f < 3136) {
            float4 v = x4[f];
            int img = f / 49;
            int off = f - img * 49;
            float* d = &lx[img * 197 + off * 4];
            d[0] = v.x; d[1] = v.y; d[2] = v.z; d[3] = v.w;
        }
    }
    __syncthreads();
    if (tid < 64) {
        const float* im = &lx[tid * 197];
        float S[8][8];
#pragma unroll
        for (int c = 0; c < 8; ++c) S[0][c] = 0.f;
        float colacc[7];
#pragma unroll
        for (int c = 0; c < 7; ++c) colacc[c] = 0.f;
#pragma unroll
        for (int r = 0; r < 7; ++r) {
            float rowf[28];
#pragma unroll
            for (int j = 0; j < 28; ++j) rowf[j] = im[r * 28 + j];
            S[r + 1][0] = 0.f;
            float run = 0.f;
#pragma unroll
            for (int c = 0; c < 7; ++c) {
                float blk2 = rowf[2 * c] + rowf[2 * c + 1] + rowf[14 + 2 * c] + rowf[14 + 2 * c + 1];
                colacc[c] += blk2;
                run += colacc[c];
                S[r + 1][c + 1] = run;
            }
        }
        const int bc = blk * 64 + tid;
#pragma unroll
        for (int k = 0; k < 64; ++k)
            Sws[(size_t)k * NBC + bc] = S[k >> 3][k & 7];
    }
}

// ---------------- Kernel B: LDS-resident S/W, lane=stream serial argmax ----------------
__global__ __launch_bounds__(512) void kernB(const float* __restrict__ Sws,
                                             unsigned long long* __restrict__ part) {
    __shared__ float Sc[64][65];                         // [c][k], stride 65 (odd)
    __shared__ float W[64][27];                          // [c][j], stride 27 (odd)
    const int tid = threadIdx.x;
    const int b = blockIdx.x >> 4;
    const int wc = blockIdx.x & 15;
    const int c0 = (wc == 15) ? 936 : wc * 64;           // chunk 15 overlaps 14
    const int cl = tid & 63;
    const int hi = tid >> 6;                             // 0..7

    // Phase 1: stage S (coalesced global read; LDS write banks (cl+k)%32: 2-way max)
#pragma unroll
    for (int it = 0; it < 8; ++it) {
        const int k = it * 8 + hi;
        Sc[cl][k] = Sws[(size_t)k * NBC + b * NC + c0 + cl];
    }
    __syncthreads();

    // Phase 2: W[c][0..24] window sums (R2 FP order), W[c][25]=total, W[c][26]=0
#pragma unroll
    for (int j = hi; j < 27; j += 8) {
        float v;
        if (j < 25) {
            const int p1 = j / 5, p2 = j % 5;
            v = ((Sc[cl][(p1 + 3) * 8 + p2 + 3] - Sc[cl][p1 * 8 + p2 + 3])
                 - Sc[cl][(p1 + 3) * 8 + p2]) + Sc[cl][p1 * 8 + p2];
        } else if (j == 25) {
            v = Sc[cl][63];                              // total
        } else {
            v = 0.f;
        }
        W[cl][j] = v;
    }
    __syncthreads();

    // Phase 3: lane = stream sid (0..350 active; 351..511 skip)
    const int sid = tid;
    if (sid < 351) {
        int pi, qi, i0, i1, i2, i3;
        if (sid < 325) {
            int p = 0;
            while (tri_off(p + 1) <= sid) ++p;           // <=24 iters, once
            const int q = p + (sid - tri_off(p));
            const int p1 = p / 5, p2 = p % 5, q1 = q / 5, q2 = q % 5;
            const int rlo = (p1 > q1 ? p1 : q1);
            const int rmn = (p1 < q1 ? p1 : q1);
            const int rhi = (rmn + 3 > rlo ? rmn + 3 : rlo);
            const int clo = (p2 > q2 ? p2 : q2);
            const int cmn = (p2 < q2 ? p2 : q2);
            const int chi = (cmn + 3 > clo ? cmn + 3 : clo);
            pi = p; qi = q;
            i0 = rhi * 8 + chi; i1 = rlo * 8 + chi;
            i2 = rhi * 8 + clo; i3 = rlo * 8 + clo;
        } else if (sid < 350) {
            pi = sid - 325; qi = 26;                     // W[c][26]=0
            i0 = i1 = i2 = i3 = 0;                       // Sc[c][0]=S[0][0]=0 -> rect=0
        } else {
            pi = 26; qi = 26; i0 = i1 = i2 = i3 = 0;     // total stream
        }
        // v = ((total - w[p]) - w[q]) + (((S[i0]-S[i1]) - S[i2]) + S[i3])  (R2 order)
        float bv = -3.4e38f;
        int bc = 0;
#pragma unroll 4
        for (int c = 0; c < 64; ++c) {
            const float rect = ((Sc[c][i0] - Sc[c][i1]) - Sc[c][i2]) + Sc[c][i3];
            const float v = ((W[c][25] - W[c][pi]) - W[c][qi]) + rect;
            if (v > bv) { bv = v; bc = c; }              // strict >: first-index
        }
        const unsigned u = __float_as_uint(bv);
        const unsigned fk = u ^ (unsigned)(((int)u >> 31) | 0x80000000);
        part[(size_t)(b * NCH + wc) * PSTRIDE + sid] =
            ((unsigned long long)fk << 32) | (unsigned)~(unsigned)(c0 + bc);
    }
}

// ---------------- Kernel C: merge chunks + final decision ----------------
__global__ __launch_bounds__(128) void kernC(const unsigned long long* __restrict__ part,
                                             int* __restrict__ out) {
    __shared__ unsigned long long mg[352];
    const int b = blockIdx.x;
    const int t = threadIdx.x;
    for (int s = t; s < 351; s += 128) {
        unsigned long long m = 0ull;
#pragma unroll
        for (int wc = 0; wc < NCH; ++wc) {
            unsigned long long v = part[(size_t)(b * NCH + wc) * PSTRIDE + s];
            if (v > m) m = v;
        }
        mg[s] = m;
    }
    __syncthreads();
    if (t < 64) {
        const unsigned predidx = (unsigned)mg[350];
        const int pred = (int)~predidx;
        bool cand = false;
        int p1 = 0;
        if (t < 25) {
            const unsigned p1i = (unsigned)mg[325 + t];
            p1 = (int)~p1i;
            bool ag = true;
            for (int j = 0; j < 25; ++j) {
                const int a = t < j ? t : j;
                const int q = t < j ? j : t;
                ag = ag && ((unsigned)mg[tri_off(a) + (q - a)] == p1i);
            }
            cand = ag && (p1 != pred);
        }
        const unsigned long long mask = __ballot(cand);
        int ans = pred;
        if (mask) ans = __shfl(p1, __ffsll(mask) - 1, 64);
        if (t == 0) out[b] = ans;
    }
}

extern "C" void kernel_launch(void* const* d_in, const int* in_sizes, int n_in,
                              void* d_out, int out_size, void* d_ws, size_t ws_size,
                              hipStream_t stream) {
    const float* x = (const float*)d_in[0];
    int* out = (int*)d_out;

    float* Sws = (float*)d_ws;                                    // 8.192 MB
    unsigned long long* part =
        (unsigned long long*)((char*)d_ws + (size_t)64 * NBC * 4); // 32*16*384*8 = 1.57 MB

    satA<<<NBC / 64, 256, 0, stream>>>(x, Sws);
    kernB<<<32 * NCH, 512, 0, stream>>>(Sws, part);
    kernC<<<32, 128, 0, stream>>>(part, out);
}

// Round 9
// 83.031 us; speedup vs baseline: 1.9077x; 1.0144x over previous
//
#include <hip/hip_runtime.h>

// SecurePooling: x (32,1000,14,14) f32 -> pred (32,) int32
// Even-coordinate SAT S[r][c] = sum(x[0:2r,0:2c]), r,c in 0..7 is a complete
// sufficient statistic. 351 streams per b: 325 unordered pairs (two[p][q]),
// 25 one-mask, 1 total.  Argmax over c per stream, first-index tie-break.
//
// R9: satA fused into kernB. Block = (b, 64-class chunk), 384 threads:
//   P0: stage 64 raw images (49 KB) into LDS, coalesced float4.
//   P1: 64 threads compute even-SAT IN-PLACE (S row r+1 overwrites consumed
//       words 8r+8..8r+15 <= read frontier 28r+27).  Sc[c][k] = lx[c*197+k].
//   P2: W[c][27] = {25 window sums, total, 0}.
//   P3: lane = stream, serial argmax over 64 c's (no cross-lane, ~15 regs).
// Kills the 8.2 MB Sws round-trip + one launch.  LDS = 56 KB, 2 blocks/CU.

#define NC 1000
#define NCH 16      // c-chunks of 64 (chunk 15 overlaps: c0=936)
#define PSTRIDE 384

__host__ __device__ constexpr int tri_off(int p) { return p * 25 - p * (p - 1) / 2; }

// ---------------- Kernel B: fused SAT + stream argmax ----------------
__global__ __launch_bounds__(384) void kernB(const float* __restrict__ x,
                                             unsigned long long* __restrict__ part) {
    __shared__ float lx[64 * 197];                       // images; later Sc overlay
    __shared__ float W[64][27];                          // {w[25], total, 0}
    const int tid = threadIdx.x;
    const int b = blockIdx.x >> 4;
    const int wc = blockIdx.x & 15;
    const int c0 = (wc == 15) ? 936 : wc * 64;           // chunk 15 overlaps 14
    const int cl = tid & 63;
    const int hi = tid >> 6;                             // 0..5

    // ---- P0: stage 64 images = 3136 float4, coalesced ----
    const float4* x4 = reinterpret_cast<const float4*>(x)
                       + (size_t)(b * NC + c0) * 49;
#pragma unroll
    for (int it = 0; it < 9; ++it) {
        const int f = it * 384 + tid;
        if (f < 3136) {
            float4 v = x4[f];
            const int img = f / 49;
            const int off = f - img * 49;
            float* d = &lx[img * 197 + off * 4];
            d[0] = v.x; d[1] = v.y; d[2] = v.z; d[3] = v.w;
        }
    }
    __syncthreads();

    // ---- P1: in-place even SAT per image (identical arithmetic to satA) ----
    if (tid < 64) {
        float* row = &lx[tid * 197];
        float colacc[7];
#pragma unroll
        for (int c = 0; c < 7; ++c) colacc[c] = 0.f;
#pragma unroll
        for (int r = 0; r < 7; ++r) {
            float rowf[28];
#pragma unroll
            for (int j = 0; j < 28; ++j) rowf[j] = row[r * 28 + j];
            if (r == 0) {
#pragma unroll
                for (int j = 0; j < 8; ++j) row[j] = 0.f;    // S row 0
            }
            row[(r + 1) * 8] = 0.f;                          // S[r+1][0]
            float run = 0.f;
#pragma unroll
            for (int c = 0; c < 7; ++c) {
                const float blk2 = rowf[2 * c] + rowf[2 * c + 1]
                                 + rowf[14 + 2 * c] + rowf[14 + 2 * c + 1];
                colacc[c] += blk2;
                run += colacc[c];
                row[(r + 1) * 8 + c + 1] = run;
            }
        }
    }
    __syncthreads();

    // ---- P2: W[c][0..24] window sums (R2 FP order), W[c][25]=total, W[c][26]=0
#define SC(c, k) lx[(c) * 197 + (k)]
#pragma unroll
    for (int j = hi; j < 27; j += 6) {
        float v;
        if (j < 25) {
            const int p1 = j / 5, p2 = j % 5;
            v = ((SC(cl, (p1 + 3) * 8 + p2 + 3) - SC(cl, p1 * 8 + p2 + 3))
                 - SC(cl, (p1 + 3) * 8 + p2)) + SC(cl, p1 * 8 + p2);
        } else if (j == 25) {
            v = SC(cl, 63);                              // total
        } else {
            v = 0.f;
        }
        W[cl][j] = v;
    }
    __syncthreads();

    // ---- P3: lane = stream sid (0..350 active) ----
    const int sid = tid;
    if (sid < 351) {
        int pi, qi, i0, i1, i2, i3;
        if (sid < 325) {
            int p = 0;
            while (tri_off(p + 1) <= sid) ++p;           // once, <=24 iters
            const int q = p + (sid - tri_off(p));
            const int p1 = p / 5, p2 = p % 5, q1 = q / 5, q2 = q % 5;
            const int rlo = (p1 > q1 ? p1 : q1);
            const int rmn = (p1 < q1 ? p1 : q1);
            const int rhi = (rmn + 3 > rlo ? rmn + 3 : rlo);
            const int clo = (p2 > q2 ? p2 : q2);
            const int cmn = (p2 < q2 ? p2 : q2);
            const int chi = (cmn + 3 > clo ? cmn + 3 : clo);
            pi = p; qi = q;
            i0 = rhi * 8 + chi; i1 = rlo * 8 + chi;
            i2 = rhi * 8 + clo; i3 = rlo * 8 + clo;
        } else if (sid < 350) {
            pi = sid - 325; qi = 26;                     // W[c][26]=0
            i0 = i1 = i2 = i3 = 0;                       // SC(c,0)=0 -> rect=0
        } else {
            pi = 26; qi = 26; i0 = i1 = i2 = i3 = 0;     // total stream
        }
        // v = ((total - w[p]) - w[q]) + (((S[i0]-S[i1]) - S[i2]) + S[i3])
        float bv = -3.4e38f;
        int bc = 0;
#pragma unroll 4
        for (int c = 0; c < 64; ++c) {
            const float rect = ((SC(c, i0) - SC(c, i1)) - SC(c, i2)) + SC(c, i3);
            const float v = ((W[c][25] - W[c][pi]) - W[c][qi]) + rect;
            if (v > bv) { bv = v; bc = c; }              // strict >: first-index
        }
        const unsigned u = __float_as_uint(bv);
        const unsigned fk = u ^ (unsigned)(((int)u >> 31) | 0x80000000);
        part[(size_t)(b * NCH + wc) * PSTRIDE + sid] =
            ((unsigned long long)fk << 32) | (unsigned)~(unsigned)(c0 + bc);
    }
#undef SC
}

// ---------------- Kernel C: merge chunks + final decision ----------------
__global__ __launch_bounds__(128) void kernC(const unsigned long long* __restrict__ part,
                                             int* __restrict__ out) {
    __shared__ unsigned long long mg[352];
    const int b = blockIdx.x;
    const int t = threadIdx.x;
    for (int s = t; s < 351; s += 128) {
        unsigned long long m = 0ull;
#pragma unroll
        for (int wc = 0; wc < NCH; ++wc) {
            unsigned long long v = part[(size_t)(b * NCH + wc) * PSTRIDE + s];
            if (v > m) m = v;
        }
        mg[s] = m;
    }
    __syncthreads();
    if (t < 64) {
        const unsigned predidx = (unsigned)mg[350];
        const int pred = (int)~predidx;
        bool cand = false;
        int p1 = 0;
        if (t < 25) {
            const unsigned p1i = (unsigned)mg[325 + t];
            p1 = (int)~p1i;
            bool ag = true;
            for (int j = 0; j < 25; ++j) {
                const int a = t < j ? t : j;
                const int q = t < j ? j : t;
                ag = ag && ((unsigned)mg[tri_off(a) + (q - a)] == p1i);
            }
            cand = ag && (p1 != pred);
        }
        const unsigned long long mask = __ballot(cand);
        int ans = pred;
        if (mask) ans = __shfl(p1, __ffsll(mask) - 1, 64);
        if (t == 0) out[b] = ans;
    }
}

extern "C" void kernel_launch(void* const* d_in, const int* in_sizes, int n_in,
                              void* d_out, int out_size, void* d_ws, size_t ws_size,
                              hipStream_t stream) {
    const float* x = (const float*)d_in[0];
    int* out = (int*)d_out;

    unsigned long long* part = (unsigned long long*)d_ws;  // 32*16*384*8 = 1.57 MB

    kernB<<<32 * NCH, 384, 0, stream>>>(x, part);
    kernC<<<32, 128, 0, stream>>>(part, out);
}